// Round 10
// baseline (166.435 us; speedup 1.0000x reference)
//
#include <hip/hip_runtime.h>
#include <hip/hip_bf16.h>

// TriangleAttentionStartingNode  B=1, N=256, C_Z=128, H=4, D=32, TOTAL=128
// Round 15: round 14 with 16 waves/block (1024 thr) - the TLP test r11/r12
// never validly ran (both spilled; r14's live set at 4-jt granularity is
// ~100 VGPR which FITS the 128-cap that 16 waves/CU needs).
//   - wave = (h = w>>2, quarter = w&3): 64 j-rows each (half the r14 chain)
//   - eb prefetched one kh ahead (r11-proven pattern, no spill at this size)
//   - everything else r14-verbatim: P in regs via 16-wide k-tiles + MFMA16,
//     G-proj after attention, xn precomputed, EbF=exp(bias) zero-acc QK,
//     weights direct from global, 3 barriers, LDS 128 KB (K+VT), Qtmp
//     overlays the wave's OWN K quarter-region, gvals bounce overlays KL.

#define QSCALE 0.17677669529663687f  // 1/sqrt(32)

typedef __attribute__((ext_vector_type(8))) short bf16x8;
typedef __attribute__((ext_vector_type(4))) short bf16x4;
typedef __attribute__((ext_vector_type(4))) float f32x4;

#define MFMA32(a, b, c) __builtin_amdgcn_mfma_f32_16x16x32_bf16((a), (b), (c), 0, 0, 0)

__device__ __forceinline__ f32x4 mfma16_asm(bf16x4 a, bf16x4 b, f32x4 c) {
    f32x4 d;
    asm volatile("v_mfma_f32_16x16x16_bf16 %0, %1, %2, %3"
                 : "=v"(d) : "v"(a), "v"(b), "v"(c));
    return d;
}

#if !defined(__HIP_DEVICE_COMPILE__)
#define MFMA16(a, b, c) (c)   /* host pass: parsed only, never executed */
#elif __has_builtin(__builtin_amdgcn_mfma_f32_16x16x16bf16_1k)
#define MFMA16(a, b, c) __builtin_amdgcn_mfma_f32_16x16x16bf16_1k((a), (b), (c), 0, 0, 0)
#else
#define MFMA16(a, b, c) mfma16_asm((a), (b), (c))
#endif

__device__ __forceinline__ ushort f2bf(float f) {
    uint32_t u = __builtin_bit_cast(uint32_t, f);
    uint32_t r = (u + 0x7FFFu + ((u >> 16) & 1u)) >> 16;  // RNE
    return (ushort)r;
}
__device__ __forceinline__ uint pk2(float a, float b) {   // v_cvt_pk_bf16_f32
    union { __hip_bfloat162 h; uint u; } cv;
    cv.h = __float22bfloat162_rn(make_float2(a, b));
    return cv.u;
}

// ---------------------------------------------------------------------------
// prep_bias (r14-verbatim): bid<320 -> Wfrag/WoFrag pack; bid>=320 -> LN ->
// xn bf16 [p][128] + EbF = exp(bias) fp32 in attn-frag order.
// ---------------------------------------------------------------------------
__global__ __launch_bounds__(256) void prep_bias_kernel(
    const float* __restrict__ Wq, const float* __restrict__ Wk, const float* __restrict__ Wv,
    const float* __restrict__ Wg, const float* __restrict__ Wo, const float* __restrict__ Wb,
    const float* __restrict__ x, const float* __restrict__ gamma, const float* __restrict__ beta,
    ushort* __restrict__ Wfrag, ushort* __restrict__ WoFrag,
    ushort* __restrict__ xn, float* __restrict__ EbF)
{
    __shared__ float WbS[512];
    __shared__ float gS[128];
    __shared__ float bS[128];

    if (blockIdx.x < 320) {
        int idx = blockIdx.x * 256 + threadIdx.x;
        if (idx < 65536) {
            int j = idx & 7, lane = (idx >> 3) & 63, ks = (idx >> 9) & 3, ct = idx >> 11;
            int n = ct * 16 + (lane & 15);
            int k = ks * 32 + (lane >> 4) * 8 + j;
            float v;
            if (n < 128)      v = Wq[k * 128 + n] * QSCALE;
            else if (n < 256) v = Wk[k * 128 + (n - 128)];
            else if (n < 384) v = Wv[k * 128 + (n - 256)];
            else              v = Wg[k * 128 + (n - 384)];
            Wfrag[idx] = f2bf(v);
        } else {
            int idx2 = idx - 65536;
            int j = idx2 & 7, lane = (idx2 >> 3) & 63, ks = (idx2 >> 9) & 3, ct = idx2 >> 11;
            int n = ct * 16 + (lane & 15);
            int k = ks * 32 + (lane >> 4) * 8 + j;
            WoFrag[idx2] = f2bf(Wo[k * 128 + n]);
        }
        return;
    }

    const int t = threadIdx.x;
    if (t < 128)      { *(f32x4*)&WbS[t * 4] = *(const f32x4*)(Wb + t * 4); }
    else if (t < 160) { int c = (t - 128) * 4; *(f32x4*)&gS[c] = *(const f32x4*)(gamma + c); }
    else if (t < 192) { int c = (t - 160) * 4; *(f32x4*)&bS[c] = *(const f32x4*)(beta + c); }
    __syncthreads();

    const int wave = t >> 6, lane = t & 63, m = lane & 15, quad = lane >> 4;
    const int p = (blockIdx.x - 320) * 64 + wave * 16 + m;

    const float* rp0 = x + (size_t)p * 128;
    f32x4 xa[4][2];
    float sum = 0.f, ssq = 0.f;
#pragma unroll
    for (int ks = 0; ks < 4; ++ks) {
        xa[ks][0] = *(const f32x4*)(rp0 + ks * 32 + quad * 8);
        xa[ks][1] = *(const f32x4*)(rp0 + ks * 32 + quad * 8 + 4);
#pragma unroll
        for (int q4 = 0; q4 < 2; ++q4) {
            f32x4 v = xa[ks][q4];
            sum += v[0] + v[1] + v[2] + v[3];
            ssq += v[0]*v[0] + v[1]*v[1] + v[2]*v[2] + v[3]*v[3];
        }
    }
    sum += __shfl_xor(sum, 16); ssq += __shfl_xor(ssq, 16);
    sum += __shfl_xor(sum, 32); ssq += __shfl_xor(ssq, 32);
    const float mu   = sum * (1.f / 128.f);
    const float rstd = rsqrtf(ssq * (1.f / 128.f) - mu * mu + 1e-5f);

    float b0 = 0.f, b1 = 0.f, b2 = 0.f, b3 = 0.f;
#pragma unroll
    for (int ks = 0; ks < 4; ++ks) {
        uint4 pkd;
        uint pw[4];
#pragma unroll
        for (int q4 = 0; q4 < 2; ++q4) {
            const int c = ks * 32 + quad * 8 + q4 * 4;
            f32x4 v = xa[ks][q4];
            float n0 = (v[0] - mu) * rstd * gS[c + 0] + bS[c + 0];
            float n1 = (v[1] - mu) * rstd * gS[c + 1] + bS[c + 1];
            float n2 = (v[2] - mu) * rstd * gS[c + 2] + bS[c + 2];
            float n3 = (v[3] - mu) * rstd * gS[c + 3] + bS[c + 3];
            pw[q4 * 2]     = pk2(n0, n1);
            pw[q4 * 2 + 1] = pk2(n2, n3);
            f32x4 w0 = *(const f32x4*)&WbS[(c + 0) * 4];
            f32x4 w1 = *(const f32x4*)&WbS[(c + 1) * 4];
            f32x4 w2 = *(const f32x4*)&WbS[(c + 2) * 4];
            f32x4 w3 = *(const f32x4*)&WbS[(c + 3) * 4];
            b0 += n0*w0[0] + n1*w1[0] + n2*w2[0] + n3*w3[0];
            b1 += n0*w0[1] + n1*w1[1] + n2*w2[1] + n3*w3[1];
            b2 += n0*w0[2] + n1*w1[2] + n2*w2[2] + n3*w3[2];
            b3 += n0*w0[3] + n1*w1[3] + n2*w2[3] + n3*w3[3];
        }
        pkd.x = pw[0]; pkd.y = pw[1]; pkd.z = pw[2]; pkd.w = pw[3];
        *(uint4*)(xn + (size_t)p * 128 + ks * 32 + quad * 8) = pkd;
    }
    b0 += __shfl_xor(b0, 16); b1 += __shfl_xor(b1, 16); b2 += __shfl_xor(b2, 16); b3 += __shfl_xor(b3, 16);
    b0 += __shfl_xor(b0, 32); b1 += __shfl_xor(b1, 32); b2 += __shfl_xor(b2, 32); b3 += __shfl_xor(b3, 32);

    if (quad == 0) {
        const int row = p >> 8, col = p & 255;
        float bb[4] = {b0, b1, b2, b3};
#pragma unroll
        for (int r = 0; r < 4; ++r) {
            int addr = (((r * 16 + (row >> 4)) * 16 + (col >> 4)) * 64 +
                        ((col & 15) >> 2) * 16 + (row & 15)) * 4 + (col & 3);
            EbF[addr] = __expf(bb[r]);
        }
    }
}

// ---------------------------------------------------------------------------
// fused: grid 256 (block = pair-row i), 1024 thr = 16 waves.
// wave w: h = w>>2, quarter = w&3; owns j-rows [quarter*64, quarter*64+64).
// LDS 131072 B: KL 64 KB (per-wave Qtmp [64][32] overlay at the wave's OWN
// K quarter-region KL + h*8192 + quarter*2048; K [4][128][64] swz; gvals
// [256][128] swz for fused oproj), VT 64 KB ([4][32][256] swz).
// launch_bounds(1024,4): cap 128 VGPR; live set ~100 -> no spill.
// ---------------------------------------------------------------------------
__global__ __launch_bounds__(1024, 4) void fused_kernel(
    const ushort* __restrict__ xn, const ushort* __restrict__ Wfrag,
    const float* __restrict__ bg, const float* __restrict__ EbF,
    const ushort* __restrict__ WoFrag, const float* __restrict__ bo,
    float* __restrict__ out)
{
    extern __shared__ __align__(16) ushort SM[];
    ushort* KL = SM;            // 32768 ushorts
    ushort* VT = SM + 32768;    // 32768 ushorts

    const f32x4 ZERO4 = {0.f, 0.f, 0.f, 0.f};

    const int t = threadIdx.x;
    const int w = t >> 6, lane = t & 63, m = lane & 15, quad = lane >> 4;
    const int i = blockIdx.x;
    const int h = w >> 2, quarter = w & 3;
    const int jbase = quarter * 64;
    const int qreg = h * 8192 + quarter * 2048;   // wave's K quarter-region
    const ushort* xb = xn + ((size_t)i << 15);    // i*256*128

    // ---- Q proj -> per-wave Qtmp [64][32] at KL + qreg ----
    {
        const ushort* Wm = Wfrag + (h * 2) * 2048;
        bf16x8 wfr[2][4];
#pragma unroll
        for (int ctl = 0; ctl < 2; ++ctl)
#pragma unroll
            for (int ks = 0; ks < 4; ++ks)
                wfr[ctl][ks] = *(const bf16x8*)(Wm + ctl * 2048 + ks * 512 + lane * 8);
#pragma unroll
        for (int grp = 0; grp < 4; ++grp) {
            const int jloc = grp * 16 + m;
            bf16x8 xg[4];
            const ushort* xp = xb + (size_t)(jbase + jloc) * 128 + quad * 8;
#pragma unroll
            for (int ks = 0; ks < 4; ++ks) xg[ks] = *(const bf16x8*)(xp + ks * 32);
#pragma unroll
            for (int ctl = 0; ctl < 2; ++ctl) {
                f32x4 acc = ZERO4;
#pragma unroll
                for (int ks = 0; ks < 4; ++ks) acc = MFMA32(wfr[ctl][ks], xg[ks], acc);
                const int c = ctl * 16 + quad * 4;
                const int idx = (qreg + jloc * 32 + c) ^ ((jloc & 3) << 3);
                uint2 u; u.x = pk2(acc[0], acc[1]); u.y = pk2(acc[2], acc[3]);
                *(uint2*)(KL + idx) = u;
            }
        }
    }
    // qf: own region, program order (ds ordering within wave)
    bf16x8 qf[4];
#pragma unroll
    for (int jt = 0; jt < 4; ++jt) {
        const int jloc = jt * 16 + m;
        const int idx = (qreg + jloc * 32 + quad * 8) ^ ((jloc & 3) << 3);
        qf[jt] = *(const bf16x8*)(KL + idx);
    }
    asm volatile("" ::: "memory");

    // ---- K proj -> K [h][k/2][64] swz; wave's k rows == its own Qtmp region
    {
        const ushort* Wm = Wfrag + (8 + h * 2) * 2048;
        bf16x8 wfr[2][4];
#pragma unroll
        for (int ctl = 0; ctl < 2; ++ctl)
#pragma unroll
            for (int ks = 0; ks < 4; ++ks)
                wfr[ctl][ks] = *(const bf16x8*)(Wm + ctl * 2048 + ks * 512 + lane * 8);
#pragma unroll
        for (int grp = 0; grp < 4; ++grp) {
            const int k = jbase + grp * 16 + m;
            bf16x8 xg[4];
            const ushort* xp = xb + (size_t)k * 128 + quad * 8;
#pragma unroll
            for (int ks = 0; ks < 4; ++ks) xg[ks] = *(const bf16x8*)(xp + ks * 32);
#pragma unroll
            for (int ctl = 0; ctl < 2; ++ctl) {
                f32x4 acc = ZERO4;
#pragma unroll
                for (int ks = 0; ks < 4; ++ks) acc = MFMA32(wfr[ctl][ks], xg[ks], acc);
                const int d0 = ctl * 16 + quad * 4;
                const int idx = (h * 8192 + (k >> 1) * 64 + (k & 1) * 32 + d0) ^ (((k >> 1) & 7) << 3);
                uint2 u; u.x = pk2(acc[0], acc[1]); u.y = pk2(acc[2], acc[3]);
                *(uint2*)(KL + idx) = u;
            }
        }
    }

    // ---- V proj -> VT [h][d][k] swz (transposed scalar stores) ----
    {
        const ushort* Wm = Wfrag + (16 + h * 2) * 2048;
        bf16x8 wfr[2][4];
#pragma unroll
        for (int ctl = 0; ctl < 2; ++ctl)
#pragma unroll
            for (int ks = 0; ks < 4; ++ks)
                wfr[ctl][ks] = *(const bf16x8*)(Wm + ctl * 2048 + ks * 512 + lane * 8);
#pragma unroll
        for (int grp = 0; grp < 4; ++grp) {
            const int k = jbase + grp * 16 + m;
            bf16x8 xg[4];
            const ushort* xp = xb + (size_t)k * 128 + quad * 8;
#pragma unroll
            for (int ks = 0; ks < 4; ++ks) xg[ks] = *(const bf16x8*)(xp + ks * 32);
#pragma unroll
            for (int ctl = 0; ctl < 2; ++ctl) {
                f32x4 acc = ZERO4;
#pragma unroll
                for (int ks = 0; ks < 4; ++ks) acc = MFMA32(wfr[ctl][ks], xg[ks], acc);
#pragma unroll
                for (int r = 0; r < 4; ++r) {
                    const int d = ctl * 16 + quad * 4 + r;
                    const int idx = ((h * 32 + d) * 256 + k) ^ ((d & 7) << 3);
                    VT[idx] = f2bf(acc[r]);
                }
            }
        }
    }
    __syncthreads();    // K, VT visible to all waves

    // ---- attention: 16-wide k-tiles; P in regs; eb prefetched 1 kh ahead --
    f32x4 O[4][2];
    float lsum[4];
#pragma unroll
    for (int jt = 0; jt < 4; ++jt) {
        O[jt][0] = ZERO4;
        O[jt][1] = ZERO4;
        lsum[jt] = 0.f;
    }
    const float* ebB = EbF + ((size_t)(h * 16 + quarter * 4) << 12) + (lane << 2);

    f32x4 ebc[4], ebn[4];
#pragma unroll
    for (int jt = 0; jt < 4; ++jt) ebc[jt] = *(const f32x4*)(ebB + (jt << 12));

    for (int kh = 0; kh < 16; ++kh) {
        if (kh < 15) {
#pragma unroll
            for (int jt = 0; jt < 4; ++jt)
                ebn[jt] = *(const f32x4*)(ebB + (jt << 12) + ((kh + 1) << 8));
        }
        const int k = kh * 16 + m;
        const int kidx = (h * 8192 + (k >> 1) * 64 + (k & 1) * 32 + quad * 8) ^ (((k >> 1) & 7) << 3);
        bf16x8 kf = *(const bf16x8*)(KL + kidx);            // A: lane=k, elems=d
        bf16x4 vf[2];                                       // A: lane=d, elems=k
#pragma unroll
        for (int dt = 0; dt < 2; ++dt) {
            const int d = dt * 16 + m;
            const int vidx = ((h * 32 + d) * 256 + kh * 16 + quad * 4) ^ ((d & 7) << 3);
            uint2 vv = *(const uint2*)(VT + vidx);
            vf[dt] = __builtin_bit_cast(bf16x4, vv);
        }
#pragma unroll
        for (int jt = 0; jt < 4; ++jt) {
            f32x4 S = MFMA32(kf, qf[jt], ZERO4);
            float p0 = __expf(S[0]) * ebc[jt][0];
            float p1 = __expf(S[1]) * ebc[jt][1];
            float p2 = __expf(S[2]) * ebc[jt][2];
            float p3 = __expf(S[3]) * ebc[jt][3];
            lsum[jt] += p0 + p1 + p2 + p3;
            uint2 pu; pu.x = pk2(p0, p1); pu.y = pk2(p2, p3);
            bf16x4 pf = __builtin_bit_cast(bf16x4, pu);     // B: lane=j, k=quad*4+e
#pragma unroll
            for (int dt = 0; dt < 2; ++dt)
                O[jt][dt] = MFMA16(vf[dt], pf, O[jt][dt]);
        }
#pragma unroll
        for (int jt = 0; jt < 4; ++jt) ebc[jt] = ebn[jt];
    }

    // row sums across quads
#pragma unroll
    for (int jt = 0; jt < 4; ++jt) {
        float s = lsum[jt];
        s += __shfl_xor(s, 16);
        s += __shfl_xor(s, 32);
        lsum[jt] = 1.f / s;
    }

    // ---- G proj + gate in registers (G acc layout == O acc layout) ----
    uint2 gva[4][2];
    {
        const ushort* Wm = Wfrag + (24 + h * 2) * 2048;
        bf16x8 wfr[2][4];
        f32x4 bg4[2];
#pragma unroll
        for (int ctl = 0; ctl < 2; ++ctl) {
#pragma unroll
            for (int ks = 0; ks < 4; ++ks)
                wfr[ctl][ks] = *(const bf16x8*)(Wm + ctl * 2048 + ks * 512 + lane * 8);
            bg4[ctl] = *(const f32x4*)(bg + h * 32 + ctl * 16 + quad * 4);
        }
#pragma unroll
        for (int grp = 0; grp < 4; ++grp) {
            const float rl = lsum[grp];
            bf16x8 xg[4];
            const ushort* xp = xb + (size_t)(jbase + grp * 16 + m) * 128 + quad * 8;
#pragma unroll
            for (int ks = 0; ks < 4; ++ks) xg[ks] = *(const bf16x8*)(xp + ks * 32);
#pragma unroll
            for (int ctl = 0; ctl < 2; ++ctl) {
                f32x4 acc = ZERO4;
#pragma unroll
                for (int ks = 0; ks < 4; ++ks) acc = MFMA32(wfr[ctl][ks], xg[ks], acc);
                float g0 = 1.f / (1.f + __expf(-(acc[0] + bg4[ctl][0])));
                float g1 = 1.f / (1.f + __expf(-(acc[1] + bg4[ctl][1])));
                float g2 = 1.f / (1.f + __expf(-(acc[2] + bg4[ctl][2])));
                float g3 = 1.f / (1.f + __expf(-(acc[3] + bg4[ctl][3])));
                float v0 = O[grp][ctl][0] * rl * g0;
                float v1 = O[grp][ctl][1] * rl * g1;
                float v2 = O[grp][ctl][2] * rl * g2;
                float v3 = O[grp][ctl][3] * rl * g3;
                gva[grp][ctl].x = pk2(v0, v1);
                gva[grp][ctl].y = pk2(v2, v3);
            }
        }
    }
    __syncthreads();    // all attention K/VT reads done before KL overwrite

    // ---- gvals -> KL [256][128] swz ----
#pragma unroll
    for (int grp = 0; grp < 4; ++grp) {
        const int j = jbase + grp * 16 + m;
#pragma unroll
        for (int ctl = 0; ctl < 2; ++ctl) {
            const int c0 = h * 32 + ctl * 16 + quad * 4;
            const int idx = (j * 128 + c0) ^ ((j & 7) << 3);
            *(uint2*)(KL + idx) = gva[grp][ctl];
        }
    }
    __syncthreads();    // gvals complete

    // ---- oproj: wave w -> rows w*16..w*16+15; Wo frags direct from global --
    bf16x8 gf[4];
    {
        const int pl = w * 16 + m;
#pragma unroll
        for (int ks = 0; ks < 4; ++ks) {
            const int idx = (pl * 128 + ks * 32 + quad * 8) ^ ((pl & 7) << 3);
            gf[ks] = *(const bf16x8*)(KL + idx);
        }
    }
#pragma unroll
    for (int ct = 0; ct < 8; ++ct) {
        bf16x8 wfr[4];
#pragma unroll
        for (int ks = 0; ks < 4; ++ks)
            wfr[ks] = *(const bf16x8*)(WoFrag + (ct * 4 + ks) * 512 + lane * 8);
        const int c0 = ct * 16 + quad * 4;
        f32x4 bov = *(const f32x4*)(bo + c0);
        f32x4 acc = ZERO4;
#pragma unroll
        for (int ks = 0; ks < 4; ++ks) acc = MFMA32(wfr[ks], gf[ks], acc);
        const int p = i * 256 + w * 16 + m;
        float4 v = make_float4(acc[0] + bov[0], acc[1] + bov[1],
                               acc[2] + bov[2], acc[3] + bov[3]);
        *(float4*)(out + (size_t)p * 128 + c0) = v;
    }
}

// ---------------------------------------------------------------------------
extern "C" void kernel_launch(void* const* d_in, const int* in_sizes, int n_in,
                              void* d_out, int out_size, void* d_ws, size_t ws_size,
                              hipStream_t stream) {
    const float* x     = (const float*)d_in[0];
    const float* gamma = (const float*)d_in[1];
    const float* beta  = (const float*)d_in[2];
    const float* Wq    = (const float*)d_in[3];
    const float* Wk    = (const float*)d_in[4];
    const float* Wv    = (const float*)d_in[5];
    const float* Wb    = (const float*)d_in[6];
    const float* Wg    = (const float*)d_in[7];
    const float* bg    = (const float*)d_in[8];
    const float* Wo    = (const float*)d_in[9];
    const float* bo    = (const float*)d_in[10];

    ushort* ws      = (ushort*)d_ws;
    ushort* Wfrag   = ws;                                // 65536 ushorts
    ushort* WoFragp = ws + 65536;                        // 16384 ushorts
    ushort* xn      = ws + 81920;                        // 8388608 ushorts (16 MB)
    float*  EbF     = (float*)(ws + 81920 + 8388608);    // 262144 fp32 (1 MB)

    static bool attr_set = false;
    if (!attr_set) {
        (void)hipFuncSetAttribute((const void*)fused_kernel,
                                  hipFuncAttributeMaxDynamicSharedMemorySize, 131072);
        attr_set = true;
    }

    prep_bias_kernel<<<1344, 256, 0, stream>>>(Wq, Wk, Wv, Wg, Wo, Wb,
                                               x, gamma, beta,
                                               Wfrag, WoFragp, xn, EbF);
    fused_kernel<<<256, 1024, 131072, stream>>>(xn, Wfrag, bg, EbF,
                                                WoFragp, bo, (float*)d_out);
}